// Round 6
// baseline (884.572 us; speedup 1.0000x reference)
//
#include <hip/hip_runtime.h>
#include <hip/hip_bf16.h>

// B=4, S=1024, D=4096, H=32, HD=128.
// INPUTS AND OUTPUT ARE FP32 (per reference). Internal compute in bf16 MFMA.
// Zero workspace; dead fp32 input buffers hold bf16 intermediates (two 32MB halves per 64MB buf).
// GEMMs: 256x256 8-phase template (T1+T2+T3+T4+T5). RoPE fused into Q/K GEMM epilogues.
// Launches: cvt{wk,wv} -> cvt{x,wq,wo} -> gemm_qkv(z=3, rope on K,Q) -> attn -> gemm_out.

typedef __bf16 bf16_t;
typedef bf16_t bf16x8 __attribute__((ext_vector_type(8)));
typedef bf16_t bf16x4 __attribute__((ext_vector_type(4)));
typedef bf16_t bf16x2 __attribute__((ext_vector_type(2)));
typedef float  f32x4  __attribute__((ext_vector_type(4)));

#define DDIM 4096
#define NTILES 64                    // K / 64
#define NEG_INF (-__builtin_inff())
#define MFMA16(a,b,c) __builtin_amdgcn_mfma_f32_16x16x32_bf16(a,b,c,0,0,0)

__device__ __forceinline__ void gl_lds16(const bf16_t* g, bf16_t* l) {
    __builtin_amdgcn_global_load_lds((__attribute__((address_space(1))) void*)(g),
                                     (__attribute__((address_space(3))) void*)(l), 16, 0, 0);
}

// ---------------- fp32 -> bf16 elementwise, up to 3 jobs per launch (blockIdx.y) --------
__global__ __launch_bounds__(256)
void cvt3_k(const float* __restrict__ s0, bf16_t* __restrict__ d0,
            const float* __restrict__ s1, bf16_t* __restrict__ d1,
            const float* __restrict__ s2, bf16_t* __restrict__ d2, int n8)
{
    const float* src; bf16_t* dst;
    if (blockIdx.y == 0)      { src = s0; dst = d0; }
    else if (blockIdx.y == 1) { src = s1; dst = d1; }
    else                      { src = s2; dst = d2; }
    const int stride = gridDim.x * 256;
    for (int i = blockIdx.x * 256 + threadIdx.x; i < n8; i += stride) {
        const float* s = src + (size_t)i * 8;
        f32x4 a = *(const f32x4*)(s);
        f32x4 b = *(const f32x4*)(s + 4);
        bf16x8 o;
        o[0] = (bf16_t)a.x; o[1] = (bf16_t)a.y; o[2] = (bf16_t)a.z; o[3] = (bf16_t)a.w;
        o[4] = (bf16_t)b.x; o[5] = (bf16_t)b.y; o[6] = (bf16_t)b.z; o[7] = (bf16_t)b.w;
        *(bf16x8*)(dst + (size_t)i * 8) = o;
    }
}

// ================= 256x256 8-phase GEMM body: C = A @ W^T =================
// LDS per buffer: A[256][64] (elems 0..16383) + B[256][64] (16384..32767).
// T2 swizzle (both-sides involution): physical 16B-block p of row holds logical
// block p ^ (row&7). global_load_lds dest linear; source pre-swizzled.
// Half-tiles: 0=B rows 0-127, 1=B rows 128-255, 2=A rows of quadrants 0,1,
// 3=A rows of quadrants 2,3. Staging tile t: ph0 -> (t+1)h3 into other buf;
// ph1/2/3 -> (t+2)h0/1/2 into CURRENT buf (regions dead by then).
// vmcnt(6) once per tile keeps 3 half-tiles in flight.

__device__ __forceinline__ void stage_half(const bf16_t* __restrict__ A,
    const bf16_t* __restrict__ Bm, int m0, int n0, int kt, int hh,
    bf16_t* __restrict__ sb, int wave, int lane)
{
#pragma unroll
    for (int j = 0; j < 2; ++j) {
        const int chunk = wave * 2 + j;                 // 16 chunks x 8 rows
        int row0;
        if (hh == 0)      row0 = chunk * 8;
        else if (hh == 1) row0 = 128 + chunk * 8;
        else if (hh == 2) row0 = (chunk < 8) ? chunk * 8 : 64 + chunk * 8;
        else              row0 = (chunk < 8) ? 64 + chunk * 8 : 128 + chunk * 8;
        const bool isB = (hh < 2);
        const int grow = (isB ? n0 : m0) + row0 + (lane >> 3);
        const int gcol = kt + (((lane & 7) ^ (lane >> 3)) << 3);   // pre-swizzled source
        const bf16_t* gp = (isB ? Bm : A) + (size_t)grow * DDIM + gcol;
        gl_lds16(gp, sb + (isB ? 16384 : 0) + row0 * 64);          // linear dest
    }
}

// STG: 2 = full stages + vmcnt(6); 1 = only ph0 stage of (t+1)h3 + vmcnt(0); 0 = none.
template<int STG>
__device__ __forceinline__ void ktile(const bf16_t* __restrict__ A,
    const bf16_t* __restrict__ Bm, int m0, int n0, int t,
    bf16_t* __restrict__ sb, bf16_t* __restrict__ sbn,
    int wave, int lane, int quad, int r, int wm, int wn,
    f32x4 acc[4][2][4], bf16x8 bfrag[4][2])
{
    const int kx0 = (quad ^ (r & 7)) << 3;          // kk=0: logical block quad
    const int kx1 = ((4 + quad) ^ (r & 7)) << 3;    // kk=1: logical block 4+quad
    // ---------- phase 0: load all B frags + A quadrant 0 (12 ds_reads) ----------
    {
        bf16x8 af[2][2];
#pragma unroll
        for (int nf = 0; nf < 4; ++nf) {
            const int ro = 16384 + (((wn << 6) + (nf << 4) + r) << 6);
            bfrag[nf][0] = *(const bf16x8*)(sb + ro + kx0);
            bfrag[nf][1] = *(const bf16x8*)(sb + ro + kx1);
        }
#pragma unroll
        for (int mf = 0; mf < 2; ++mf) {
            const int ro = ((wm << 7) + (mf << 4) + r) << 6;
            af[mf][0] = *(const bf16x8*)(sb + ro + kx0);
            af[mf][1] = *(const bf16x8*)(sb + ro + kx1);
        }
        if (STG >= 1) stage_half(A, Bm, m0, n0, (t + 1) << 6, 3, sbn, wave, lane);
        asm volatile("s_waitcnt lgkmcnt(8)" ::: "memory");   // template pacing (12-read phase)
        __builtin_amdgcn_sched_barrier(0);
        __builtin_amdgcn_s_barrier();
        asm volatile("s_waitcnt lgkmcnt(0)" ::: "memory");
        __builtin_amdgcn_sched_barrier(0);
        __builtin_amdgcn_s_setprio(1);
#pragma unroll
        for (int kk = 0; kk < 2; ++kk)
#pragma unroll
            for (int mf = 0; mf < 2; ++mf)
#pragma unroll
                for (int nf = 0; nf < 4; ++nf)
                    acc[0][mf][nf] = MFMA16(af[mf][kk], bfrag[nf][kk], acc[0][mf][nf]);
        __builtin_amdgcn_s_setprio(0);
        __builtin_amdgcn_sched_barrier(0);
        __builtin_amdgcn_s_barrier();
    }
    // ---------- phases 1..3: A quadrant q ----------
#pragma unroll
    for (int q = 1; q < 4; ++q) {
        bf16x8 af[2][2];
#pragma unroll
        for (int mf = 0; mf < 2; ++mf) {
            const int ro = ((wm << 7) + (q << 5) + (mf << 4) + r) << 6;
            af[mf][0] = *(const bf16x8*)(sb + ro + kx0);
            af[mf][1] = *(const bf16x8*)(sb + ro + kx1);
        }
        if (STG == 2) stage_half(A, Bm, m0, n0, (t + 2) << 6, q - 1, sb, wave, lane);
        __builtin_amdgcn_sched_barrier(0);
        __builtin_amdgcn_s_barrier();
        asm volatile("s_waitcnt lgkmcnt(0)" ::: "memory");
        __builtin_amdgcn_sched_barrier(0);
        __builtin_amdgcn_s_setprio(1);
#pragma unroll
        for (int kk = 0; kk < 2; ++kk)
#pragma unroll
            for (int mf = 0; mf < 2; ++mf)
#pragma unroll
                for (int nf = 0; nf < 4; ++nf)
                    acc[q][mf][nf] = MFMA16(af[mf][kk], bfrag[nf][kk], acc[q][mf][nf]);
        __builtin_amdgcn_s_setprio(0);
        if (q == 3) {
            if (STG == 2)      asm volatile("s_waitcnt vmcnt(6)" ::: "memory");
            else if (STG == 1) asm volatile("s_waitcnt vmcnt(0)" ::: "memory");
        }
        __builtin_amdgcn_sched_barrier(0);
        __builtin_amdgcn_s_barrier();
    }
}

template<bool C_F32>
__device__ __forceinline__ void gemm_body(const bf16_t* __restrict__ A,
    const bf16_t* __restrict__ Bm, void* __restrict__ Cv,
    const float* __restrict__ fc, const float* __restrict__ fs, bool doRope)
{
    __shared__ __attribute__((aligned(16))) bf16_t sm[2 * 32768];   // 128 KiB
    const int tid  = threadIdx.x;
    const int wave = tid >> 6, lane = tid & 63;
    const int quad = lane >> 4, r = lane & 15;
    const int wm = wave >> 2, wn = wave & 3;
    // T1: bijective XCD swizzle (256 WGs, 8 XCDs -> 32 each, m-contiguous)
    const int swz = ((int)blockIdx.x % 8) * 32 + (int)blockIdx.x / 8;
    const int m0 = (swz >> 4) << 8, n0 = (swz & 15) << 8;

    f32x4 acc[4][2][4] = {};
    bf16x8 bfrag[4][2];

    // prologue: tile0 all halves -> buf0; tile1 halves 0..2 -> buf1; wait tile0.
#pragma unroll
    for (int hh = 0; hh < 4; ++hh) stage_half(A, Bm, m0, n0, 0, hh, sm, wave, lane);
#pragma unroll
    for (int hh = 0; hh < 3; ++hh) stage_half(A, Bm, m0, n0, 64, hh, sm + 32768, wave, lane);
    asm volatile("s_waitcnt vmcnt(6)" ::: "memory");
    __builtin_amdgcn_s_barrier();

#pragma unroll 2
    for (int t = 0; t < NTILES - 2; ++t) {
        bf16_t* sb  = sm + ((t & 1) ? 32768 : 0);
        bf16_t* sbn = sm + ((t & 1) ? 0 : 32768);
        ktile<2>(A, Bm, m0, n0, t, sb, sbn, wave, lane, quad, r, wm, wn, acc, bfrag);
    }
    ktile<1>(A, Bm, m0, n0, NTILES - 2, sm, sm + 32768, wave, lane, quad, r, wm, wn, acc, bfrag);
    ktile<0>(A, Bm, m0, n0, NTILES - 1, sm + 32768, sm, wave, lane, quad, r, wm, wn, acc, bfrag);

    // epilogue: C/D layout col = lane&15, row = quad*4 + reg.
    // Fused RoPE (Q/K): col f = n0 + wn*64 + nf*16 + r; pairs (even,odd) in lanes r, r^1.
    // Pair index p = (f mod 128)>>1 = (wn&1)*32 + nf*8 + (r>>1)  [wn*64 mod 128 = (wn&1)*64].
    // Token s = row & 1023.
    const float sgn = (r & 1) ? 1.0f : -1.0f;
#pragma unroll
    for (int q = 0; q < 4; ++q)
#pragma unroll
        for (int mf = 0; mf < 2; ++mf)
#pragma unroll
            for (int reg = 0; reg < 4; ++reg) {
                const int grow = m0 + (wm << 7) + (q << 5) + (mf << 4) + (quad << 2) + reg;
                const size_t rowoff = (size_t)grow * DDIM;
                const int s = grow & 1023;
#pragma unroll
                for (int nf = 0; nf < 4; ++nf) {
                    float v = acc[q][mf][nf][reg];
                    if (doRope) {
                        const int p = ((wn & 1) << 5) + (nf << 3) + (r >> 1);
                        const float c  = fc[s * 64 + p];
                        const float sn = fs[s * 64 + p];
                        const float partner = __shfl_xor(v, 1);
                        v = v * c + sgn * partner * sn;
                    }
                    const size_t idx = rowoff + n0 + (wn << 6) + (nf << 4) + r;
                    if constexpr (C_F32) ((float*)Cv)[idx] = v;
                    else                 ((bf16_t*)Cv)[idx] = (bf16_t)v;
                }
            }
}

// Merged QKV GEMM: blockIdx.z selects {0:K(rope), 1:V, 2:Q(rope)}.
__global__ __launch_bounds__(512, 2)
void gemm_qkv(const bf16_t* __restrict__ A,
              const bf16_t* __restrict__ b0, const bf16_t* __restrict__ b1,
              const bf16_t* __restrict__ b2,
              bf16_t* __restrict__ c0, bf16_t* __restrict__ c1, bf16_t* __restrict__ c2,
              const float* __restrict__ fc, const float* __restrict__ fs)
{
    const int sel = blockIdx.z;
    const bf16_t* Bm = (sel == 0) ? b0 : (sel == 1) ? b1 : b2;
    bf16_t*       Cv = (sel == 0) ? c0 : (sel == 1) ? c1 : c2;
    gemm_body<false>(A, Bm, Cv, fc, fs, sel != 1);
}

// Output projection: fp32 C, no rope.
__global__ __launch_bounds__(512, 2)
void gemm_out(const bf16_t* __restrict__ A, const bf16_t* __restrict__ Bm,
              float* __restrict__ Cv)
{
    gemm_body<true>(A, Bm, Cv, nullptr, nullptr, false);
}

// ---------------- causal flash attention, all bf16 (verified round 3/4) ----------------
__global__ __launch_bounds__(256, 2)
void attn_k(const bf16_t* __restrict__ qm, const bf16_t* __restrict__ km,
            const bf16_t* __restrict__ vm, bf16_t* __restrict__ om)
{
    constexpr int BQ = 128, BT = 64;
    constexpr int PS = 80;
    __shared__ __attribute__((aligned(16))) bf16_t sK[BT * 128];
    __shared__ __attribute__((aligned(16))) bf16_t sVt[128 * 64];
    __shared__ __attribute__((aligned(16))) bf16_t sP[4][32 * PS];
    const int tid = threadIdx.x, wave = tid >> 6, lane = tid & 63;
    const int quad = lane >> 4, r = lane & 15;
    const int b = blockIdx.x >> 5, h = blockIdx.x & 31;
    const int q0 = (7 - (int)blockIdx.y) * BQ;
    const int qw = q0 + wave * 32;
    const float scale = 0.08838834764831845f;

    bf16x8 qf[2][4];
#pragma unroll
    for (int mt = 0; mt < 2; ++mt)
#pragma unroll
        for (int kk = 0; kk < 4; ++kk)
            qf[mt][kk] = *(const bf16x8*)(qm + (size_t)(b * 1024 + qw + mt * 16 + r) * DDIM
                                          + h * 128 + kk * 32 + quad * 8);

    f32x4 oacc[2][8] = {};
    float m_i[2][4], l_i[2][4];
#pragma unroll
    for (int mt = 0; mt < 2; ++mt)
#pragma unroll
        for (int reg = 0; reg < 4; ++reg) { m_i[mt][reg] = NEG_INF; l_i[mt][reg] = 0.f; }

    const bf16_t* gKb = km + (size_t)(b * 1024 + wave * 16 + quad) * DDIM + h * 128;
    const int rp = tid >> 3, cseg = tid & 7;

    for (int t0 = 0; t0 < q0 + BQ; t0 += BT) {
#pragma unroll
        for (int i = 0; i < 4; ++i) {
            const int xv = (i * 4 + quad) & 7;
            gl_lds16(gKb + (size_t)(t0 + i * 4) * DDIM + ((r ^ xv) << 3),
                     sK + (wave * 4 + i) * 512);
        }
        {
            const bf16_t* gv = vm + (size_t)(b * 1024 + t0 + 2 * rp) * DDIM + h * 128 + cseg * 16;
            bf16x8 v00 = *(const bf16x8*)(gv);
            bf16x8 v01 = *(const bf16x8*)(gv + 8);
            bf16x8 v10 = *(const bf16x8*)(gv + DDIM);
            bf16x8 v11 = *(const bf16x8*)(gv + DDIM + 8);
#pragma unroll
            for (int e = 0; e < 8; ++e) {
                bf16x2 w0, w1;
                w0.x = v00[e]; w0.y = v10[e];
                w1.x = v01[e]; w1.y = v11[e];
                const int pb = ((((rp >> 2) ^ (e ^ cseg)) & 7) << 3) + ((rp & 3) << 1);
                *(bf16x2*)(sVt + (cseg * 16 + e) * 64 + pb) = w0;
                *(bf16x2*)(sVt + (cseg * 16 + 8 + e) * 64 + pb) = w1;
            }
        }
        __syncthreads();

        f32x4 sacc[2][4] = {};
#pragma unroll
        for (int kk = 0; kk < 4; ++kk) {
            bf16x8 kf[4];
#pragma unroll
            for (int nt = 0; nt < 4; ++nt)
                kf[nt] = *(const bf16x8*)(sK + (nt * 16 + r) * 128
                                          + (((kk * 4 + quad) ^ (r & 7)) << 3));
#pragma unroll
            for (int mt = 0; mt < 2; ++mt)
#pragma unroll
                for (int nt = 0; nt < 4; ++nt)
                    sacc[mt][nt] = MFMA16(qf[mt][kk], kf[nt], sacc[mt][nt]);
        }

#pragma unroll
        for (int mt = 0; mt < 2; ++mt) {
#pragma unroll
            for (int reg = 0; reg < 4; ++reg) {
                const int qrow = qw + mt * 16 + quad * 4 + reg;
                float mx = NEG_INF;
#pragma unroll
                for (int nt = 0; nt < 4; ++nt) {
                    const int tcol = t0 + nt * 16 + r;
                    float v = sacc[mt][nt][reg] * scale;
                    v = (tcol <= qrow) ? v : NEG_INF;
                    sacc[mt][nt][reg] = v;
                    mx = fmaxf(mx, v);
                }
                mx = fmaxf(mx, __shfl_xor(mx, 1));
                mx = fmaxf(mx, __shfl_xor(mx, 2));
                mx = fmaxf(mx, __shfl_xor(mx, 4));
                mx = fmaxf(mx, __shfl_xor(mx, 8));
                if (!__all(mx - m_i[mt][reg] <= 8.0f)) {
                    const float mnew = fmaxf(m_i[mt][reg], mx);
                    const float alpha = __expf(m_i[mt][reg] - mnew);
                    m_i[mt][reg] = mnew;
                    l_i[mt][reg] *= alpha;
#pragma unroll
                    for (int nt = 0; nt < 8; ++nt)
                        oacc[mt][nt][reg] *= alpha;
                }
                float rs = 0.f;
#pragma unroll
                for (int nt = 0; nt < 4; ++nt) {
                    const float pv = __expf(sacc[mt][nt][reg] - m_i[mt][reg]);
                    rs += pv;
                    sP[wave][(mt * 16 + quad * 4 + reg) * PS + nt * 16 + r] = (bf16_t)pv;
                }
                rs += __shfl_xor(rs, 1);
                rs += __shfl_xor(rs, 2);
                rs += __shfl_xor(rs, 4);
                rs += __shfl_xor(rs, 8);
                l_i[mt][reg] += rs;
            }
        }

#pragma unroll
        for (int kk2 = 0; kk2 < 2; ++kk2) {
            bf16x8 pf[2];
#pragma unroll
            for (int mt = 0; mt < 2; ++mt)
                pf[mt] = *(const bf16x8*)(&sP[wave][(mt * 16 + r) * PS + kk2 * 32 + quad * 8]);
#pragma unroll
            for (int nt = 0; nt < 8; ++nt) {
                bf16x8 vf = *(const bf16x8*)(sVt + (nt * 16 + r) * 64
                                             + ((((kk2 * 4 + quad) ^ (r & 7) ^ nt) & 7) << 3));
#pragma unroll
                for (int mt = 0; mt < 2; ++mt)
                    oacc[mt][nt] = MFMA16(pf[mt], vf, oacc[mt][nt]);
            }
        }
        __syncthreads();
    }

#pragma unroll
    for (int mt = 0; mt < 2; ++mt)
#pragma unroll
        for (int reg = 0; reg < 4; ++reg) {
            const float inv = 1.0f / l_i[mt][reg];
            const size_t row = (size_t)(b * 1024 + qw + mt * 16 + quad * 4 + reg) * DDIM + h * 128;
#pragma unroll
            for (int nt = 0; nt < 8; ++nt)
                om[row + nt * 16 + r] = (bf16_t)(oacc[mt][nt][reg] * inv);
        }
}

extern "C" void kernel_launch(void* const* d_in, const int* in_sizes, int n_in,
                              void* d_out, int out_size, void* d_ws, size_t ws_size,
                              hipStream_t stream)
{
    (void)in_sizes; (void)n_in; (void)out_size; (void)d_ws; (void)ws_size;
    const float* x  = (const float*)d_in[0];
    const float* wq = (const float*)d_in[1];
    const float* wk = (const float*)d_in[2];
    const float* wv = (const float*)d_in[3];
    const float* wo = (const float*)d_in[4];
    const float* fc = (const float*)d_in[5];
    const float* fs = (const float*)d_in[6];
    // d_in[7] = mask: causal, implemented analytically.

    const size_t NE = (size_t)DDIM * DDIM;    // 16.7M elems = 32MB bf16
    const int n8 = (int)(NE / 8);

    bf16_t* wkb = (bf16_t*)d_out;             // d_out.lo
    bf16_t* wvb = wkb + NE;                   // d_out.hi
    bf16_t* xb  = (bf16_t*)d_in[2];           // wk_buf.lo (wk dead after cvt pass 1)
    bf16_t* wqb = xb + NE;                    // wk_buf.hi
    bf16_t* wob = (bf16_t*)d_in[3];           // wv_buf.lo (wv dead after cvt pass 1)
    bf16_t* ob  = wob + NE;                   // wv_buf.hi (attn output)
    bf16_t* kb  = (bf16_t*)d_in[1];           // wq_buf.lo (wq dead after cvt pass 2)
    bf16_t* vb  = kb + NE;                    // wq_buf.hi
    bf16_t* qb  = (bf16_t*)d_in[4];           // wo_buf.lo (wo dead after cvt pass 2)
    float*  out = (float*)d_out;

    // pass 1: dsts in d_out only (wk/wv buffers still live as sources)
    cvt3_k<<<dim3(2048, 2), 256, 0, stream>>>(wk, wkb, wv, wvb, wv, wvb, n8);
    // pass 2: dsts in wk/wv buffers (now dead); sources x, wq, wo disjoint
    cvt3_k<<<dim3(2048, 3), 256, 0, stream>>>(x, xb, wq, wqb, wo, wob, n8);

    // K (rope), V, Q (rope) in one dispatch; RoPE fused in epilogue
    gemm_qkv<<<dim3(256, 1, 3), 512, 0, stream>>>(xb, wkb, wvb, wqb, kb, vb, qb, fc, fs);
    attn_k<<<dim3(128, 8), 256, 0, stream>>>(qb, kb, vb, ob);
    gemm_out<<<256, 512, 0, stream>>>(ob, wob, out);   // out proj (fp32 out)
}

// Round 7
// 827.460 us; speedup vs baseline: 1.0690x; 1.0690x over previous
//
#include <hip/hip_runtime.h>
#include <hip/hip_bf16.h>

// B=4, S=1024, D=4096, H=32, HD=128.
// INPUTS AND OUTPUT ARE FP32 (per reference). Internal compute in bf16 MFMA.
// Zero workspace; dead fp32 input buffers hold bf16 intermediates (two 32MB halves per 64MB buf).
// GEMMs: 256x256 8-phase template (T1+T2+T3+T4+T5), 4 separate 256-block dispatches
// (z=3 merge regressed in R6). RoPE fused into K/Q GEMM epilogues (verified R6).
// attn: K double-buffered + T14 async-stage (K gl_lds + V reg-loads in flight across
// the compute phase) + T5 setprio. Core math/swizzles verified R3/R4.

typedef __bf16 bf16_t;
typedef bf16_t bf16x8 __attribute__((ext_vector_type(8)));
typedef bf16_t bf16x4 __attribute__((ext_vector_type(4)));
typedef bf16_t bf16x2 __attribute__((ext_vector_type(2)));
typedef float  f32x4  __attribute__((ext_vector_type(4)));

#define DDIM 4096
#define NTILES 64                    // K / 64
#define NEG_INF (-__builtin_inff())
#define MFMA16(a,b,c) __builtin_amdgcn_mfma_f32_16x16x32_bf16(a,b,c,0,0,0)

__device__ __forceinline__ void gl_lds16(const bf16_t* g, bf16_t* l) {
    __builtin_amdgcn_global_load_lds((__attribute__((address_space(1))) void*)(g),
                                     (__attribute__((address_space(3))) void*)(l), 16, 0, 0);
}

// ---------------- fp32 -> bf16 elementwise, up to 3 jobs per launch (blockIdx.y) --------
__global__ __launch_bounds__(256)
void cvt3_k(const float* __restrict__ s0, bf16_t* __restrict__ d0,
            const float* __restrict__ s1, bf16_t* __restrict__ d1,
            const float* __restrict__ s2, bf16_t* __restrict__ d2, int n8)
{
    const float* src; bf16_t* dst;
    if (blockIdx.y == 0)      { src = s0; dst = d0; }
    else if (blockIdx.y == 1) { src = s1; dst = d1; }
    else                      { src = s2; dst = d2; }
    const int stride = gridDim.x * 256;
    for (int i = blockIdx.x * 256 + threadIdx.x; i < n8; i += stride) {
        const float* s = src + (size_t)i * 8;
        f32x4 a = *(const f32x4*)(s);
        f32x4 b = *(const f32x4*)(s + 4);
        bf16x8 o;
        o[0] = (bf16_t)a.x; o[1] = (bf16_t)a.y; o[2] = (bf16_t)a.z; o[3] = (bf16_t)a.w;
        o[4] = (bf16_t)b.x; o[5] = (bf16_t)b.y; o[6] = (bf16_t)b.z; o[7] = (bf16_t)b.w;
        *(bf16x8*)(dst + (size_t)i * 8) = o;
    }
}

// ================= 256x256 8-phase GEMM body: C = A @ W^T =================
// (verified R4 @ 124.6us/dispatch, MfmaUtil 49.5, bank-conflict 0)

__device__ __forceinline__ void stage_half(const bf16_t* __restrict__ A,
    const bf16_t* __restrict__ Bm, int m0, int n0, int kt, int hh,
    bf16_t* __restrict__ sb, int wave, int lane)
{
#pragma unroll
    for (int j = 0; j < 2; ++j) {
        const int chunk = wave * 2 + j;                 // 16 chunks x 8 rows
        int row0;
        if (hh == 0)      row0 = chunk * 8;
        else if (hh == 1) row0 = 128 + chunk * 8;
        else if (hh == 2) row0 = (chunk < 8) ? chunk * 8 : 64 + chunk * 8;
        else              row0 = (chunk < 8) ? 64 + chunk * 8 : 128 + chunk * 8;
        const bool isB = (hh < 2);
        const int grow = (isB ? n0 : m0) + row0 + (lane >> 3);
        const int gcol = kt + (((lane & 7) ^ (lane >> 3)) << 3);   // pre-swizzled source
        const bf16_t* gp = (isB ? Bm : A) + (size_t)grow * DDIM + gcol;
        gl_lds16(gp, sb + (isB ? 16384 : 0) + row0 * 64);          // linear dest
    }
}

// STG: 2 = full stages + vmcnt(6); 1 = only ph0 stage of (t+1)h3 + vmcnt(0); 0 = none.
template<int STG>
__device__ __forceinline__ void ktile(const bf16_t* __restrict__ A,
    const bf16_t* __restrict__ Bm, int m0, int n0, int t,
    bf16_t* __restrict__ sb, bf16_t* __restrict__ sbn,
    int wave, int lane, int quad, int r, int wm, int wn,
    f32x4 acc[4][2][4], bf16x8 bfrag[4][2])
{
    const int kx0 = (quad ^ (r & 7)) << 3;          // kk=0: logical block quad
    const int kx1 = ((4 + quad) ^ (r & 7)) << 3;    // kk=1: logical block 4+quad
    // ---------- phase 0: load all B frags + A quadrant 0 (12 ds_reads) ----------
    {
        bf16x8 af[2][2];
#pragma unroll
        for (int nf = 0; nf < 4; ++nf) {
            const int ro = 16384 + (((wn << 6) + (nf << 4) + r) << 6);
            bfrag[nf][0] = *(const bf16x8*)(sb + ro + kx0);
            bfrag[nf][1] = *(const bf16x8*)(sb + ro + kx1);
        }
#pragma unroll
        for (int mf = 0; mf < 2; ++mf) {
            const int ro = ((wm << 7) + (mf << 4) + r) << 6;
            af[mf][0] = *(const bf16x8*)(sb + ro + kx0);
            af[mf][1] = *(const bf16x8*)(sb + ro + kx1);
        }
        if (STG >= 1) stage_half(A, Bm, m0, n0, (t + 1) << 6, 3, sbn, wave, lane);
        asm volatile("s_waitcnt lgkmcnt(8)" ::: "memory");   // template pacing (12-read phase)
        __builtin_amdgcn_sched_barrier(0);
        __builtin_amdgcn_s_barrier();
        asm volatile("s_waitcnt lgkmcnt(0)" ::: "memory");
        __builtin_amdgcn_sched_barrier(0);
        __builtin_amdgcn_s_setprio(1);
#pragma unroll
        for (int kk = 0; kk < 2; ++kk)
#pragma unroll
            for (int mf = 0; mf < 2; ++mf)
#pragma unroll
                for (int nf = 0; nf < 4; ++nf)
                    acc[0][mf][nf] = MFMA16(af[mf][kk], bfrag[nf][kk], acc[0][mf][nf]);
        __builtin_amdgcn_s_setprio(0);
        __builtin_amdgcn_sched_barrier(0);
        __builtin_amdgcn_s_barrier();
    }
    // ---------- phases 1..3: A quadrant q ----------
#pragma unroll
    for (int q = 1; q < 4; ++q) {
        bf16x8 af[2][2];
#pragma unroll
        for (int mf = 0; mf < 2; ++mf) {
            const int ro = ((wm << 7) + (q << 5) + (mf << 4) + r) << 6;
            af[mf][0] = *(const bf16x8*)(sb + ro + kx0);
            af[mf][1] = *(const bf16x8*)(sb + ro + kx1);
        }
        if (STG == 2) stage_half(A, Bm, m0, n0, (t + 2) << 6, q - 1, sb, wave, lane);
        __builtin_amdgcn_sched_barrier(0);
        __builtin_amdgcn_s_barrier();
        asm volatile("s_waitcnt lgkmcnt(0)" ::: "memory");
        __builtin_amdgcn_sched_barrier(0);
        __builtin_amdgcn_s_setprio(1);
#pragma unroll
        for (int kk = 0; kk < 2; ++kk)
#pragma unroll
            for (int mf = 0; mf < 2; ++mf)
#pragma unroll
                for (int nf = 0; nf < 4; ++nf)
                    acc[q][mf][nf] = MFMA16(af[mf][kk], bfrag[nf][kk], acc[q][mf][nf]);
        __builtin_amdgcn_s_setprio(0);
        if (q == 3) {
            if (STG == 2)      asm volatile("s_waitcnt vmcnt(6)" ::: "memory");
            else if (STG == 1) asm volatile("s_waitcnt vmcnt(0)" ::: "memory");
        }
        __builtin_amdgcn_sched_barrier(0);
        __builtin_amdgcn_s_barrier();
    }
}

template<bool C_F32, bool ROPE>
__device__ __forceinline__ void gemm_body(const bf16_t* __restrict__ A,
    const bf16_t* __restrict__ Bm, void* __restrict__ Cv,
    const float* __restrict__ fc, const float* __restrict__ fs)
{
    __shared__ __attribute__((aligned(16))) bf16_t sm[2 * 32768];   // 128 KiB
    const int tid  = threadIdx.x;
    const int wave = tid >> 6, lane = tid & 63;
    const int quad = lane >> 4, r = lane & 15;
    const int wm = wave >> 2, wn = wave & 3;
    // T1: bijective XCD swizzle (256 WGs, 8 XCDs -> 32 each, m-contiguous)
    const int swz = ((int)blockIdx.x % 8) * 32 + (int)blockIdx.x / 8;
    const int m0 = (swz >> 4) << 8, n0 = (swz & 15) << 8;

    f32x4 acc[4][2][4] = {};
    bf16x8 bfrag[4][2];

    // prologue: tile0 all halves -> buf0; tile1 halves 0..2 -> buf1; wait tile0.
#pragma unroll
    for (int hh = 0; hh < 4; ++hh) stage_half(A, Bm, m0, n0, 0, hh, sm, wave, lane);
#pragma unroll
    for (int hh = 0; hh < 3; ++hh) stage_half(A, Bm, m0, n0, 64, hh, sm + 32768, wave, lane);
    asm volatile("s_waitcnt vmcnt(6)" ::: "memory");
    __builtin_amdgcn_s_barrier();

#pragma unroll 2
    for (int t = 0; t < NTILES - 2; ++t) {
        bf16_t* sb  = sm + ((t & 1) ? 32768 : 0);
        bf16_t* sbn = sm + ((t & 1) ? 0 : 32768);
        ktile<2>(A, Bm, m0, n0, t, sb, sbn, wave, lane, quad, r, wm, wn, acc, bfrag);
    }
    ktile<1>(A, Bm, m0, n0, NTILES - 2, sm, sm + 32768, wave, lane, quad, r, wm, wn, acc, bfrag);
    ktile<0>(A, Bm, m0, n0, NTILES - 1, sm + 32768, sm, wave, lane, quad, r, wm, wn, acc, bfrag);

    // epilogue: C/D layout col = lane&15, row = quad*4 + reg.
    // Fused RoPE (K/Q): col f = n0 + wn*64 + nf*16 + r; pairs (even,odd) in lanes r, r^1.
    // p = (f mod 128)>>1 = (wn&1)*32 + nf*8 + (r>>1). Token s = row & 1023.
    const float sgn = (r & 1) ? 1.0f : -1.0f;
#pragma unroll
    for (int q = 0; q < 4; ++q)
#pragma unroll
        for (int mf = 0; mf < 2; ++mf)
#pragma unroll
            for (int reg = 0; reg < 4; ++reg) {
                const int grow = m0 + (wm << 7) + (q << 5) + (mf << 4) + (quad << 2) + reg;
                const size_t rowoff = (size_t)grow * DDIM;
                const int s = grow & 1023;
#pragma unroll
                for (int nf = 0; nf < 4; ++nf) {
                    float v = acc[q][mf][nf][reg];
                    if constexpr (ROPE) {
                        const int p = ((wn & 1) << 5) + (nf << 3) + (r >> 1);
                        const float c  = fc[s * 64 + p];
                        const float sn = fs[s * 64 + p];
                        const float partner = __shfl_xor(v, 1);
                        v = v * c + sgn * partner * sn;
                    }
                    const size_t idx = rowoff + n0 + (wn << 6) + (nf << 4) + r;
                    if constexpr (C_F32) ((float*)Cv)[idx] = v;
                    else                 ((bf16_t*)Cv)[idx] = (bf16_t)v;
                }
            }
}

__global__ __launch_bounds__(512, 2)
void gemm_rope(const bf16_t* __restrict__ A, const bf16_t* __restrict__ Bm,
               bf16_t* __restrict__ Cv, const float* __restrict__ fc,
               const float* __restrict__ fs)
{
    gemm_body<false, true>(A, Bm, Cv, fc, fs);
}

__global__ __launch_bounds__(512, 2)
void gemm_plain(const bf16_t* __restrict__ A, const bf16_t* __restrict__ Bm,
                bf16_t* __restrict__ Cv)
{
    gemm_body<false, false>(A, Bm, Cv, nullptr, nullptr);
}

__global__ __launch_bounds__(512, 2)
void gemm_out(const bf16_t* __restrict__ A, const bf16_t* __restrict__ Bm,
              float* __restrict__ Cv)
{
    gemm_body<true, false>(A, Bm, Cv, nullptr, nullptr);
}

// ---------------- causal flash attention, all bf16 ----------------
// grid (B*H=128, S/BQ=8); q0 = (7-y)*128 gives LPT order. 4 waves x 32 q-rows.
// T14: K(t+1) gl_lds (into sK[buf^1]) and V(t+1) global->reg issued after the
// stage barrier, in flight across QK^T/softmax/PV, drained by next iteration's
// __syncthreads. V regs written to sVt after that barrier (write-late).
__global__ __launch_bounds__(256, 2)
void attn_k(const bf16_t* __restrict__ qm, const bf16_t* __restrict__ km,
            const bf16_t* __restrict__ vm, bf16_t* __restrict__ om)
{
    constexpr int BQ = 128, BT = 64;
    constexpr int PS = 80;
    __shared__ __attribute__((aligned(16))) bf16_t sK[2][BT * 128];   // dbuf, 2x16KB
    __shared__ __attribute__((aligned(16))) bf16_t sVt[128 * 64];
    __shared__ __attribute__((aligned(16))) bf16_t sP[4][32 * PS];
    const int tid = threadIdx.x, wave = tid >> 6, lane = tid & 63;
    const int quad = lane >> 4, r = lane & 15;
    const int b = blockIdx.x >> 5, h = blockIdx.x & 31;
    const int q0 = (7 - (int)blockIdx.y) * BQ;
    const int qw = q0 + wave * 32;
    const float scale = 0.08838834764831845f;   // 1/sqrt(128)

    bf16x8 qf[2][4];
#pragma unroll
    for (int mt = 0; mt < 2; ++mt)
#pragma unroll
        for (int kk = 0; kk < 4; ++kk)
            qf[mt][kk] = *(const bf16x8*)(qm + (size_t)(b * 1024 + qw + mt * 16 + r) * DDIM
                                          + h * 128 + kk * 32 + quad * 8);

    f32x4 oacc[2][8] = {};
    float m_i[2][4], l_i[2][4];
#pragma unroll
    for (int mt = 0; mt < 2; ++mt)
#pragma unroll
        for (int reg = 0; reg < 4; ++reg) { m_i[mt][reg] = NEG_INF; l_i[mt][reg] = 0.f; }

    // K staging: wave's rows t = wave*16 + i*4 + quad; lane r loads logical block r^xv
    const bf16_t* gKb = km + (size_t)(b * 1024 + wave * 16 + quad) * DDIM + h * 128;
    const int rp = tid >> 3, cseg = tid & 7;
    const bf16_t* gVb = vm + (size_t)(b * 1024 + 2 * rp) * DDIM + h * 128 + cseg * 16;

    // prologue: issue K(0) -> sK[0], V(0) -> regs
    bf16x8 v00, v01, v10, v11;
#pragma unroll
    for (int i = 0; i < 4; ++i) {
        const int xv = (i * 4 + quad) & 7;
        gl_lds16(gKb + (size_t)(i * 4) * DDIM + ((r ^ xv) << 3),
                 sK[0] + (wave * 4 + i) * 512);
    }
    v00 = *(const bf16x8*)(gVb);
    v01 = *(const bf16x8*)(gVb + 8);
    v10 = *(const bf16x8*)(gVb + DDIM);
    v11 = *(const bf16x8*)(gVb + DDIM + 8);

    int buf = 0;
    for (int t0 = 0; t0 < q0 + BQ; t0 += BT) {
        __syncthreads();   // (A) drains K(t)/V(t) loads; all waves past prior PV reads
        // write-late: V(t) regs -> sVt (transpose + swizzle, verified indexing)
#pragma unroll
        for (int e = 0; e < 8; ++e) {
            bf16x2 w0, w1;
            w0.x = v00[e]; w0.y = v10[e];
            w1.x = v01[e]; w1.y = v11[e];
            const int pb = ((((rp >> 2) ^ (e ^ cseg)) & 7) << 3) + ((rp & 3) << 1);
            *(bf16x2*)(sVt + (cseg * 16 + e) * 64 + pb) = w0;
            *(bf16x2*)(sVt + (cseg * 16 + 8 + e) * 64 + pb) = w1;
        }
        __syncthreads();   // (B) sVt + sK[buf] visible to all

        // T14 prefetch t+1: in flight across the whole compute phase
        if (t0 + BT < q0 + BQ) {
#pragma unroll
            for (int i = 0; i < 4; ++i) {
                const int xv = (i * 4 + quad) & 7;
                gl_lds16(gKb + (size_t)(t0 + BT + i * 4) * DDIM + ((r ^ xv) << 3),
                         sK[buf ^ 1] + (wave * 4 + i) * 512);
            }
            const bf16_t* gv = gVb + (size_t)(t0 + BT) * DDIM;
            v00 = *(const bf16x8*)(gv);
            v01 = *(const bf16x8*)(gv + 8);
            v10 = *(const bf16x8*)(gv + DDIM);
            v11 = *(const bf16x8*)(gv + DDIM + 8);
        }

        f32x4 sacc[2][4] = {};
#pragma unroll
        for (int kk = 0; kk < 4; ++kk) {
            bf16x8 kf[4];
#pragma unroll
            for (int nt = 0; nt < 4; ++nt)
                kf[nt] = *(const bf16x8*)(sK[buf] + (nt * 16 + r) * 128
                                          + (((kk * 4 + quad) ^ (r & 7)) << 3));
            __builtin_amdgcn_s_setprio(1);
#pragma unroll
            for (int mt = 0; mt < 2; ++mt)
#pragma unroll
                for (int nt = 0; nt < 4; ++nt)
                    sacc[mt][nt] = MFMA16(qf[mt][kk], kf[nt], sacc[mt][nt]);
            __builtin_amdgcn_s_setprio(0);
        }

#pragma unroll
        for (int mt = 0; mt < 2; ++mt) {
#pragma unroll
            for (int reg = 0; reg < 4; ++reg) {
                const int qrow = qw + mt * 16 + quad * 4 + reg;
                float mx = NEG_INF;
#pragma unroll
                for (int nt = 0; nt < 4; ++nt) {
                    const int tcol = t0 + nt * 16 + r;
                    float v = sacc[mt][nt][reg] * scale;
                    v = (tcol <= qrow) ? v : NEG_INF;
                    sacc[mt][nt][reg] = v;
                    mx = fmaxf(mx, v);
                }
                mx = fmaxf(mx, __shfl_xor(mx, 1));
                mx = fmaxf(mx, __shfl_xor(mx, 2));
                mx = fmaxf(mx, __shfl_xor(mx, 4));
                mx = fmaxf(mx, __shfl_xor(mx, 8));
                // T13 defer-max
                if (!__all(mx - m_i[mt][reg] <= 8.0f)) {
                    const float mnew = fmaxf(m_i[mt][reg], mx);
                    const float alpha = __expf(m_i[mt][reg] - mnew);
                    m_i[mt][reg] = mnew;
                    l_i[mt][reg] *= alpha;
#pragma unroll
                    for (int nt = 0; nt < 8; ++nt)
                        oacc[mt][nt][reg] *= alpha;
                }
                float rs = 0.f;
#pragma unroll
                for (int nt = 0; nt < 4; ++nt) {
                    const float pv = __expf(sacc[mt][nt][reg] - m_i[mt][reg]);
                    rs += pv;
                    sP[wave][(mt * 16 + quad * 4 + reg) * PS + nt * 16 + r] = (bf16_t)pv;
                }
                rs += __shfl_xor(rs, 1);
                rs += __shfl_xor(rs, 2);
                rs += __shfl_xor(rs, 4);
                rs += __shfl_xor(rs, 8);
                l_i[mt][reg] += rs;
            }
        }

#pragma unroll
        for (int kk2 = 0; kk2 < 2; ++kk2) {
            bf16x8 pf[2];
#pragma unroll
            for (int mt = 0; mt < 2; ++mt)
                pf[mt] = *(const bf16x8*)(&sP[wave][(mt * 16 + r) * PS + kk2 * 32 + quad * 8]);
#pragma unroll
            for (int nt = 0; nt < 8; ++nt) {
                bf16x8 vf = *(const bf16x8*)(sVt + (nt * 16 + r) * 64
                                             + ((((kk2 * 4 + quad) ^ (r & 7) ^ nt) & 7) << 3));
                __builtin_amdgcn_s_setprio(1);
#pragma unroll
                for (int mt = 0; mt < 2; ++mt)
                    oacc[mt][nt] = MFMA16(pf[mt], vf, oacc[mt][nt]);
                __builtin_amdgcn_s_setprio(0);
            }
        }
        buf ^= 1;
    }

#pragma unroll
    for (int mt = 0; mt < 2; ++mt)
#pragma unroll
        for (int reg = 0; reg < 4; ++reg) {
            const float inv = 1.0f / l_i[mt][reg];
            const size_t row = (size_t)(b * 1024 + qw + mt * 16 + quad * 4 + reg) * DDIM + h * 128;
#pragma unroll
            for (int nt = 0; nt < 8; ++nt)
                om[row + nt * 16 + r] = (bf16_t)(oacc[mt][nt][reg] * inv);
        }
}

extern "C" void kernel_launch(void* const* d_in, const int* in_sizes, int n_in,
                              void* d_out, int out_size, void* d_ws, size_t ws_size,
                              hipStream_t stream)
{
    (void)in_sizes; (void)n_in; (void)out_size; (void)d_ws; (void)ws_size;
    const float* x  = (const float*)d_in[0];
    const float* wq = (const float*)d_in[1];
    const float* wk = (const float*)d_in[2];
    const float* wv = (const float*)d_in[3];
    const float* wo = (const float*)d_in[4];
    const float* fc = (const float*)d_in[5];
    const float* fs = (const float*)d_in[6];
    // d_in[7] = mask: causal, implemented analytically.

    const size_t NE = (size_t)DDIM * DDIM;    // 16.7M elems = 32MB bf16
    const int n8 = (int)(NE / 8);

    bf16_t* wkb = (bf16_t*)d_out;             // d_out.lo
    bf16_t* wvb = wkb + NE;                   // d_out.hi
    bf16_t* xb  = (bf16_t*)d_in[2];           // wk_buf.lo (wk dead after cvt pass 1)
    bf16_t* wqb = xb + NE;                    // wk_buf.hi
    bf16_t* wob = (bf16_t*)d_in[3];           // wv_buf.lo (wv dead after cvt pass 1)
    bf16_t* ob  = wob + NE;                   // wv_buf.hi (attn output)
    bf16_t* kb  = (bf16_t*)d_in[1];           // wq_buf.lo (wq dead after cvt pass 2)
    bf16_t* vb  = kb + NE;                    // wq_buf.hi
    bf16_t* qb  = (bf16_t*)d_in[4];           // wo_buf.lo (wo dead after cvt pass 2)
    float*  out = (float*)d_out;

    // pass 1: dsts in d_out only (wk/wv buffers still live as sources)
    cvt3_k<<<dim3(2048, 2), 256, 0, stream>>>(wk, wkb, wv, wvb, wv, wvb, n8);
    // pass 2: dsts in wk/wv buffers (now dead); sources x, wq, wo disjoint
    cvt3_k<<<dim3(2048, 3), 256, 0, stream>>>(x, xb, wq, wqb, wo, wob, n8);

    gemm_rope <<<256, 512, 0, stream>>>(xb, wkb, kb, fc, fs);   // K (rope fused)
    gemm_plain<<<256, 512, 0, stream>>>(xb, wvb, vb);           // V
    gemm_rope <<<256, 512, 0, stream>>>(xb, wqb, qb, fc, fs);   // Q (rope fused)
    attn_k<<<dim3(128, 8), 256, 0, stream>>>(qb, kb, vb, ob);
    gemm_out<<<256, 512, 0, stream>>>(ob, wob, out);            // out proj (fp32 out)
}